// Round 1
// baseline (208.458 us; speedup 1.0000x reference)
//
#include <hip/hip_runtime.h>

// YOLO loss: N=4096, S=14, B=2, NCLS=20.
// Cells = 4096*14*14 = 802816. One thread per cell, 4-way partial sums,
// wave64 + LDS reduce, atomicAdd per block into ws, epilogue scales.

#define NCELLS (4096 * 14 * 14)
#define NBLOCKS (NCELLS / 256)   // 3136, exact

// ws layout (floats): [0..3] = cls, noobj, contain, reg sums; ws[8] (as int) = mask-mode flag

__global__ void yolo_zero_kernel(float* __restrict__ ws) {
    if (threadIdx.x < 16) ws[threadIdx.x] = 0.0f;
}

// Detect whether the mask buffer is int32 (bytes 4k+1..4k+3 all zero) or
// 1-byte bool (random nonzero bytes at non-multiple-of-4 offsets).
// Scans first 4096 int32 slots = 16 KB (both layouts are larger than that).
__global__ void yolo_detect_kernel(const unsigned char* __restrict__ mb,
                                   int* __restrict__ flag) {
    int t = threadIdx.x;
    unsigned int found = 0;
#pragma unroll
    for (int k = 0; k < 16; ++k) {
        int slot = t * 16 + k;
        found |= mb[4 * slot + 1] | mb[4 * slot + 2] | mb[4 * slot + 3];
    }
    if (found) atomicOr(flag, 1);  // 1 => bool8 layout
}

__global__ __launch_bounds__(256) void yolo_main_kernel(
    const float* __restrict__ pred,
    const float* __restrict__ tbox,
    const float* __restrict__ tcls,
    const void* __restrict__ mask,
    const int* __restrict__ flag,
    float* __restrict__ ws) {
    const int c = blockIdx.x * 256 + threadIdx.x;  // grid covers NCELLS exactly

    // ---- loads (vectorized) ----
    float pv[30];
    {
        const float2* p2 = (const float2*)(pred + (long long)30 * c);  // 120B/cell -> 8B aligned
#pragma unroll
        for (int k = 0; k < 15; ++k) {
            float2 t = p2[k];
            pv[2 * k] = t.x;
            pv[2 * k + 1] = t.y;
        }
    }
    const float4 tb = *(const float4*)(tbox + (long long)4 * c);
    float tc[20];
    {
        const float4* c4 = (const float4*)(tcls + (long long)20 * c);  // 80B/cell -> 16B aligned
#pragma unroll
        for (int k = 0; k < 5; ++k) {
            float4 t = c4[k];
            tc[4 * k] = t.x;
            tc[4 * k + 1] = t.y;
            tc[4 * k + 2] = t.z;
            tc[4 * k + 3] = t.w;
        }
    }
    const int mode = *flag;  // uniform across grid
    float m;
    if (mode) {
        m = ((const unsigned char*)mask)[c] ? 1.0f : 0.0f;
    } else {
        m = ((const int*)mask)[c] ? 1.0f : 0.0f;
    }

    // ---- per-cell losses ----
    // cls: m * sum((pred_cls - target_cls)^2)
    float s = 0.0f;
#pragma unroll
    for (int i = 0; i < 20; ++i) {
        float d = pv[10 + i] - tc[i];
        s += d * d;
    }
    float cls_s = m * s;

    // no-obj: (1-m) * (conf0^2 + conf1^2)
    float conf0 = pv[4], conf1 = pv[9];
    float noobj_s = (1.0f - m) * (conf0 * conf0 + conf1 * conf1);

    // IoU per box
    float iou[2];
    float at = (tb.z - tb.x) * (tb.w - tb.y);
#pragma unroll
    for (int b = 0; b < 2; ++b) {
        int base = 5 * b;
        float x = pv[base] / 14.0f;
        float y = pv[base + 1] / 14.0f;
        float w = pv[base + 2];
        float h = pv[base + 3];
        float p1x = x - w * 0.5f, p1y = y - h * 0.5f;
        float p2x = x + w * 0.5f, p2y = y + h * 0.5f;
        float ltx = fmaxf(p1x, tb.x), lty = fmaxf(p1y, tb.y);
        float rbx = fminf(p2x, tb.z), rby = fminf(p2y, tb.w);
        float iw = fmaxf(rbx - ltx, 0.0f), ih = fmaxf(rby - lty, 0.0f);
        float inter = iw * ih;
        float ap = w * h;
        iou[b] = inter / (ap + at - inter);
    }
    // jnp.argmax: first max wins -> pick box1 only if strictly greater
    int best = (iou[1] > iou[0]) ? 5 : 0;
    float bx = pv[best], by = pv[best + 1], bw = pv[best + 2], bh = pv[best + 3],
          bc = pv[best + 4];

    float contain_s = m * (bc - 1.0f) * (bc - 1.0f);

    float dx = bx - tb.x, dy = by - tb.y;
    float dw = sqrtf(bw) - sqrtf(tb.z);
    float dh = sqrtf(bh) - sqrtf(tb.w);
    float reg_s = m * (dx * dx + dy * dy + dw * dw + dh * dh);

    // ---- reduction: wave64 shuffle -> LDS -> atomicAdd ----
#pragma unroll
    for (int off = 32; off > 0; off >>= 1) {
        cls_s += __shfl_down(cls_s, off, 64);
        noobj_s += __shfl_down(noobj_s, off, 64);
        contain_s += __shfl_down(contain_s, off, 64);
        reg_s += __shfl_down(reg_s, off, 64);
    }
    __shared__ float red[4][4];
    int lane = threadIdx.x & 63;
    int wid = threadIdx.x >> 6;
    if (lane == 0) {
        red[wid][0] = cls_s;
        red[wid][1] = noobj_s;
        red[wid][2] = contain_s;
        red[wid][3] = reg_s;
    }
    __syncthreads();
    if (threadIdx.x < 4) {
        float v = red[0][threadIdx.x] + red[1][threadIdx.x] +
                  red[2][threadIdx.x] + red[3][threadIdx.x];
        atomicAdd(&ws[threadIdx.x], v);
    }
}

__global__ void yolo_final_kernel(const float* __restrict__ ws,
                                  float* __restrict__ out) {
    if (threadIdx.x == 0) {
        const float inv_n = 1.0f / 4096.0f;
        float cls = ws[0] * inv_n;
        float noobj = ws[1] * inv_n;
        float contain = ws[2] * inv_n;
        float reg = ws[3] * inv_n;
        float total = cls + 0.5f * noobj + 5.0f * reg + contain;
        out[0] = total;
        out[1] = reg;
        out[2] = contain;
        out[3] = noobj;
        out[4] = cls;
    }
}

extern "C" void kernel_launch(void* const* d_in, const int* in_sizes, int n_in,
                              void* d_out, int out_size, void* d_ws,
                              size_t ws_size, hipStream_t stream) {
    const float* pred = (const float*)d_in[0];
    const float* tbox = (const float*)d_in[1];
    const float* tcls = (const float*)d_in[2];
    const void* mask = d_in[3];
    float* ws = (float*)d_ws;
    float* out = (float*)d_out;

    yolo_zero_kernel<<<1, 64, 0, stream>>>(ws);
    yolo_detect_kernel<<<1, 256, 0, stream>>>((const unsigned char*)mask,
                                              (int*)(ws + 8));
    yolo_main_kernel<<<NBLOCKS, 256, 0, stream>>>(pred, tbox, tcls, mask,
                                                  (const int*)(ws + 8), ws);
    yolo_final_kernel<<<1, 64, 0, stream>>>(ws, out);
}